// Round 1
// baseline (159.406 us; speedup 1.0000x reference)
//
#include <hip/hip_runtime.h>
#include <hip/hip_bf16.h>
#include <cmath>

#define R_ 64
#define B_ 4096
#define D_ 512
#define C_ 128

typedef __attribute__((ext_vector_type(8))) short bf16x8;
typedef __attribute__((ext_vector_type(4))) float f32x4;

__device__ __forceinline__ unsigned short f2bf(float f) {
  union { float f; unsigned u; } x; x.f = f;
  unsigned r = (x.u + 0x7FFFu + ((x.u >> 16) & 1u)) >> 16;
  return (unsigned short)r;
}

// ---------------- prep: x f32 -> bf16 ----------------
__global__ void prep_x_kernel(const float* __restrict__ x, unsigned short* __restrict__ xw) {
  int i = blockIdx.x * 256 + threadIdx.x;          // float4 index, exact count
  float4 v = reinterpret_cast<const float4*>(x)[i];
  ushort4 o;
  o.x = f2bf(v.x); o.y = f2bf(v.y); o.z = f2bf(v.z); o.w = f2bf(v.w);
  reinterpret_cast<ushort4*>(xw)[i] = o;
}

// ---------------- prep: W[r][d][c] f32 -> W^T[r][c][d] bf16 ----------------
__global__ void prep_w_kernel(const float* __restrict__ W, unsigned short* __restrict__ wt) {
  __shared__ float t[32][33];
  int bx = blockIdx.x;
  int r = bx >> 6;
  int rem = bx & 63;
  int d0 = (rem >> 2) << 5;   // 16 d-tiles of 32
  int c0 = (rem & 3) << 5;    // 4 c-tiles of 32
  int tx = threadIdx.x & 31, ty = threadIdx.x >> 5;  // 32 x 8
  const float* Wr = W + (size_t)r * D_ * C_;
#pragma unroll
  for (int q = 0; q < 4; ++q) {
    int dl = q * 8 + ty;
    t[dl][tx] = Wr[(size_t)(d0 + dl) * C_ + c0 + tx];
  }
  __syncthreads();
  unsigned short* wtr = wt + (size_t)r * C_ * D_;
#pragma unroll
  for (int q = 0; q < 4; ++q) {
    int cl = q * 8 + ty;
    float v = t[tx][cl];                         // transposed read, pad-33 conflict-free
    wtr[(size_t)(c0 + cl) * D_ + d0 + tx] = f2bf(v);
  }
}

// ---------------- antecedent: fs_ini + softmax -> fire ----------------
__global__ __launch_bounds__(256, 4) void fs_kernel(
    const float* __restrict__ x, const float* __restrict__ proto,
    const float* __restrict__ var, float* __restrict__ fire) {
  __shared__ float x_s[16 * 68];
  __shared__ float p_s[64 * 68];
  __shared__ float sa_s[64 * 68];
  const int tid = threadIdx.x;
  const int b0 = blockIdx.x * 16;
  const int tr = tid & 63;     // rule = lane
  const int tb = tid >> 6;     // wave -> 4 batch rows
  float facc[4] = {0.f, 0.f, 0.f, 0.f};

  for (int dc = 0; dc < D_; dc += 64) {
    __syncthreads();
    {
      int row = tid >> 4, c4 = tid & 15;  // 256 float4 chunks: 16 rows x 16
      float4 v = *reinterpret_cast<const float4*>(&x[(size_t)(b0 + row) * D_ + dc + c4 * 4]);
      *reinterpret_cast<float4*>(&x_s[row * 68 + c4 * 4]) = v;
    }
    for (int t = tid; t < 1024; t += 256) {   // 64 rows x 16 float4
      int row = t >> 4, c4 = t & 15;
      const int go = row * D_ + dc + c4 * 4;
      float4 pv = *reinterpret_cast<const float4*>(&proto[go]);
      *reinterpret_cast<float4*>(&p_s[row * 68 + c4 * 4]) = pv;
      float4 vv = *reinterpret_cast<const float4*>(&var[go]);
      float4 sv;
      // sa = sqrt(log2 e)/clip(v)  so  exp2(-(diff*sa)^2) = exp(-diff^2/v^2) = m^2
      sv.x = 1.2011224087864498f / fminf(fmaxf(vv.x, 1e-4f), 0.1f);
      sv.y = 1.2011224087864498f / fminf(fmaxf(vv.y, 1e-4f), 0.1f);
      sv.z = 1.2011224087864498f / fminf(fmaxf(vv.z, 1e-4f), 0.1f);
      sv.w = 1.2011224087864498f / fminf(fmaxf(vv.w, 1e-4f), 0.1f);
      *reinterpret_cast<float4*>(&sa_s[row * 68 + c4 * 4]) = sv;
    }
    __syncthreads();
#pragma unroll
    for (int d4 = 0; d4 < 16; ++d4) {
      float4 pv = *reinterpret_cast<const float4*>(&p_s[tr * 68 + d4 * 4]);
      float4 sv = *reinterpret_cast<const float4*>(&sa_s[tr * 68 + d4 * 4]);
#pragma unroll
      for (int i = 0; i < 4; ++i) {
        float4 xv = *reinterpret_cast<const float4*>(&x_s[(tb * 4 + i) * 68 + d4 * 4]);
        float u;
        u = (xv.x - pv.x) * sv.x; facc[i] += exp2f(-(u * u));
        u = (xv.y - pv.y) * sv.y; facc[i] += exp2f(-(u * u));
        u = (xv.z - pv.z) * sv.z; facc[i] += exp2f(-(u * u));
        u = (xv.w - pv.w) * sv.w; facc[i] += exp2f(-(u * u));
      }
    }
  }
  // softmax over rules (= lanes of the wave)
#pragma unroll
  for (int i = 0; i < 4; ++i) {
    float v = facc[i];
    float m = v;
#pragma unroll
    for (int off = 32; off; off >>= 1) m = fmaxf(m, __shfl_xor(m, off, 64));
    float e = exp2f((v - m) * 1.4426950408889634f);
    float s = e;
#pragma unroll
    for (int off = 32; off; off >>= 1) s += __shfl_xor(s, off, 64);
    fire[(size_t)(b0 + tb * 4 + i) * R_ + tr] = e / s;
  }
}

// ---------------- fused rule-GEMM + relu + fire-weighted combine ----------------
__global__ __launch_bounds__(512, 2) void gemm_kernel(
    const unsigned short* __restrict__ xw, const unsigned short* __restrict__ wt,
    const float* __restrict__ fire, const float* __restrict__ bias,
    float* __restrict__ out) {
  __shared__ __align__(16) unsigned short x_s[2][128 * 64];
  __shared__ __align__(16) unsigned short w_s[2][128 * 64];
  __shared__ float fire_s[128 * 8];
  __shared__ float bias_s[8 * 128];

  const int tid = threadIdx.x;
  const int bm = blockIdx.x;   // 0..31 batch-row block
  const int rg = blockIdx.y;   // 0..7  rule group (8 rules)
  const int b0 = bm * 128;

  {
    int t = tid;
#pragma unroll
    for (int q = 0; q < 2; ++q, t += 512) {
      int row = t >> 3, g = t & 7;
      fire_s[t] = fire[(size_t)(b0 + row) * R_ + rg * 8 + g];
    }
    t = tid;
#pragma unroll
    for (int q = 0; q < 2; ++q, t += 512) {
      bias_s[t] = bias[rg * 8 * C_ + t];
    }
  }

  const int wid = tid >> 6, lane = tid & 63;
  const int wm = wid >> 2, wn = wid & 3;           // 2 x 4 wave grid, wave tile 64x32
  const int l16 = lane & 15, lhi = lane >> 4;

  // ds_read byte offsets (XOR-swizzled granules within 128B rows)
  int offA[4][2], offB[2][2];
#pragma unroll
  for (int m = 0; m < 4; ++m) {
    int row = wm * 64 + m * 16 + l16;
#pragma unroll
    for (int ks = 0; ks < 2; ++ks)
      offA[m][ks] = row * 128 + (((ks * 4 + lhi) ^ (row & 7)) << 4);
  }
#pragma unroll
  for (int n = 0; n < 2; ++n) {
    int row = wn * 32 + n * 16 + l16;
#pragma unroll
    for (int ks = 0; ks < 2; ++ks)
      offB[n][ks] = row * 128 + (((ks * 4 + lhi) ^ (row & 7)) << 4);
  }

  const unsigned short* xsrc = xw + (size_t)b0 * D_;

  float tot[4][2][4];
#pragma unroll
  for (int m = 0; m < 4; ++m)
#pragma unroll
    for (int n = 0; n < 2; ++n)
#pragma unroll
      for (int j = 0; j < 4; ++j) tot[m][n][j] = 0.f;

  f32x4 acc[4][2];

  // stage one 128x64 bf16 tile: linear LDS dest, inverse-swizzled global source
  auto stage = [&](unsigned short* lds, const unsigned short* src, int kc) {
#pragma unroll
    for (int t2 = 0; t2 < 2; ++t2) {
      int ch = t2 * 512 + tid;          // 1024 x 16B chunks
      int row = ch >> 3, g = ch & 7;
      const unsigned short* ga = src + (size_t)row * D_ + kc + ((g ^ (row & 7)) << 3);
      __builtin_amdgcn_global_load_lds(
          (const __attribute__((address_space(1))) void*)ga,
          (__attribute__((address_space(3))) void*)(lds + ch * 8), 16, 0, 0);
    }
  };

  stage(x_s[0], xsrc, 0);
  stage(w_s[0], wt + (size_t)(rg * 8) * C_ * D_, 0);
  asm volatile("s_waitcnt vmcnt(0)" ::: "memory");
  __syncthreads();

  int cur = 0;
  for (int s = 0; s < 64; ++s) {
    const int g = s >> 3, kk = s & 7;
    if (kk == 0) {
#pragma unroll
      for (int m = 0; m < 4; ++m)
#pragma unroll
        for (int n = 0; n < 2; ++n)
          acc[m][n] = f32x4{0.f, 0.f, 0.f, 0.f};
    }
    if (s + 1 < 64) {
      const int s1 = s + 1;
      stage(x_s[cur ^ 1], xsrc, (s1 & 7) * 64);
      stage(w_s[cur ^ 1], wt + (size_t)(rg * 8 + (s1 >> 3)) * C_ * D_, (s1 & 7) * 64);
    }
    const char* xb = (const char*)x_s[cur];
    const char* wb = (const char*)w_s[cur];
    bf16x8 av[4][2], bv[2][2];
#pragma unroll
    for (int m = 0; m < 4; ++m)
#pragma unroll
      for (int ks = 0; ks < 2; ++ks)
        av[m][ks] = *reinterpret_cast<const bf16x8*>(xb + offA[m][ks]);
#pragma unroll
    for (int n = 0; n < 2; ++n)
#pragma unroll
      for (int ks = 0; ks < 2; ++ks)
        bv[n][ks] = *reinterpret_cast<const bf16x8*>(wb + offB[n][ks]);
#pragma unroll
    for (int ks = 0; ks < 2; ++ks)
#pragma unroll
      for (int m = 0; m < 4; ++m)
#pragma unroll
        for (int n = 0; n < 2; ++n)
          acc[m][n] = __builtin_amdgcn_mfma_f32_16x16x32_bf16(av[m][ks], bv[n][ks], acc[m][n], 0, 0, 0);
    if (kk == 7) {  // rule g finished: relu(+bias) * fire, accumulate
#pragma unroll
      for (int m = 0; m < 4; ++m)
#pragma unroll
        for (int n = 0; n < 2; ++n) {
          int col = wn * 32 + n * 16 + l16;
          float bi = bias_s[g * 128 + col];
#pragma unroll
          for (int j = 0; j < 4; ++j) {
            int rowl = wm * 64 + m * 16 + lhi * 4 + j;
            float v = acc[m][n][j] + bi;
            v = fmaxf(v, 0.f);
            tot[m][n][j] += v * fire_s[rowl * 8 + g];
          }
        }
    }
    asm volatile("s_waitcnt vmcnt(0)" ::: "memory");
    __syncthreads();
    cur ^= 1;
  }

#pragma unroll
  for (int m = 0; m < 4; ++m)
#pragma unroll
    for (int n = 0; n < 2; ++n) {
      int col = wn * 32 + n * 16 + l16;
#pragma unroll
      for (int j = 0; j < 4; ++j) {
        int rowl = wm * 64 + m * 16 + lhi * 4 + j;
        atomicAdd(&out[(size_t)(b0 + rowl) * C_ + col], tot[m][n][j]);
      }
    }
}

extern "C" void kernel_launch(void* const* d_in, const int* in_sizes, int n_in,
                              void* d_out, int out_size, void* d_ws, size_t ws_size,
                              hipStream_t stream) {
  const float* x     = (const float*)d_in[0];
  const float* proto = (const float*)d_in[1];
  const float* var   = (const float*)d_in[2];
  const float* W     = (const float*)d_in[3];
  const float* bias  = (const float*)d_in[4];
  float* out  = (float*)d_out;
  float* fire = out + (size_t)B_ * C_;   // second output region

  const size_t WS_X  = (size_t)B_ * D_ * sizeof(unsigned short);       // 4 MiB
  const size_t WS_WT = (size_t)R_ * C_ * D_ * sizeof(unsigned short);  // 8 MiB
  if (ws_size < WS_X + WS_WT) return;    // insufficient scratch -> visible failure

  unsigned short* xw  = (unsigned short*)d_ws;
  unsigned short* wtp = (unsigned short*)((char*)d_ws + WS_X);

  hipMemsetAsync(d_out, 0, (size_t)B_ * C_ * sizeof(float), stream);
  prep_x_kernel<<<dim3((B_ * D_ / 4) / 256), dim3(256), 0, stream>>>(x, xw);
  prep_w_kernel<<<dim3(R_ * 64), dim3(256), 0, stream>>>(W, wtp);
  fs_kernel<<<dim3(B_ / 16), dim3(256), 0, stream>>>(x, proto, var, fire);
  gemm_kernel<<<dim3(B_ / 128, R_ / 8), dim3(512), 0, stream>>>(xw, wtp, fire, bias, out);
}

// Round 2
// 133.088 us; speedup vs baseline: 1.1977x; 1.1977x over previous
//
#include <hip/hip_runtime.h>
#include <hip/hip_bf16.h>
#include <cmath>

#define R_ 64
#define B_ 4096
#define D_ 512
#define C_ 128

typedef __attribute__((ext_vector_type(8))) short bf16x8;
typedef __attribute__((ext_vector_type(4))) float f32x4;

__device__ __forceinline__ unsigned short f2bf(float f) {
  union { float f; unsigned u; } x; x.f = f;
  unsigned r = (x.u + 0x7FFFu + ((x.u >> 16) & 1u)) >> 16;
  return (unsigned short)r;
}

// ---------------- prep: x f32 -> bf16 ----------------
__global__ void prep_x_kernel(const float* __restrict__ x, unsigned short* __restrict__ xw) {
  int i = blockIdx.x * 256 + threadIdx.x;          // float4 index, exact count
  float4 v = reinterpret_cast<const float4*>(x)[i];
  ushort4 o;
  o.x = f2bf(v.x); o.y = f2bf(v.y); o.z = f2bf(v.z); o.w = f2bf(v.w);
  reinterpret_cast<ushort4*>(xw)[i] = o;
}

// ---------------- prep: W[r][d][c] f32 -> W^T[r][c][d] bf16 ----------------
__global__ void prep_w_kernel(const float* __restrict__ W, unsigned short* __restrict__ wt) {
  __shared__ float t[32][33];
  int bx = blockIdx.x;
  int r = bx >> 6;
  int rem = bx & 63;
  int d0 = (rem >> 2) << 5;   // 16 d-tiles of 32
  int c0 = (rem & 3) << 5;    // 4 c-tiles of 32
  int tx = threadIdx.x & 31, ty = threadIdx.x >> 5;  // 32 x 8
  const float* Wr = W + (size_t)r * D_ * C_;
#pragma unroll
  for (int q = 0; q < 4; ++q) {
    int dl = q * 8 + ty;
    t[dl][tx] = Wr[(size_t)(d0 + dl) * C_ + c0 + tx];
  }
  __syncthreads();
  unsigned short* wtr = wt + (size_t)r * C_ * D_;
#pragma unroll
  for (int q = 0; q < 4; ++q) {
    int cl = q * 8 + ty;
    float v = t[tx][cl];                         // transposed read, pad-33 conflict-free
    wtr[(size_t)(c0 + cl) * D_ + d0 + tx] = f2bf(v);
  }
}

// ---------------- prep: (s, -p*s) per (rule, dim) ----------------
// s = sqrt(log2 e)/clip(v)  so  exp2(-(fma(x,s,nsp))^2) = exp(-(x-p)^2/v^2) = m^2
__global__ void prep_ps_kernel(const float* __restrict__ proto, const float* __restrict__ var,
                               float* __restrict__ ps) {
  int i = blockIdx.x * 256 + threadIdx.x;          // R*D elements
  float v = fminf(fmaxf(var[i], 1e-4f), 0.1f);
  float s = 1.2011224087864498f / v;
  float2 o; o.x = s; o.y = -proto[i] * s;
  reinterpret_cast<float2*>(ps)[i] = o;
}

// ---------------- antecedent partial: fs_ini accumulation ----------------
// grid (B/16, 8): 16 batch rows x 64 rules x 64 dims per block; atomics into fire buf.
__global__ __launch_bounds__(256, 4) void fs_partial_kernel(
    const float* __restrict__ x, const float* __restrict__ ps,
    float* __restrict__ fire) {
  __shared__ float x_s[16 * 68];
  __shared__ __align__(16) float ps_s[64 * 128];   // [rule][dim*2], XOR-swizzled granules
  const int tid = threadIdx.x;
  const int b0 = blockIdx.x * 16;
  const int dq = blockIdx.y;                       // dims dq*64 .. dq*64+63

  {  // stage x tile: 16 rows x 64 dims
    int row = tid >> 4, c4 = tid & 15;
    float4 v = *reinterpret_cast<const float4*>(&x[(size_t)(b0 + row) * D_ + dq * 64 + c4 * 4]);
    *reinterpret_cast<float4*>(&x_s[row * 68 + c4 * 4]) = v;
  }
#pragma unroll
  for (int k = 0; k < 8; ++k) {  // stage ps tile: 64 rules x 32 granules(16B), swizzled
    int g = tid + k * 256;
    int row = g >> 5, gi = g & 31;
    float4 v = *reinterpret_cast<const float4*>(&ps[(size_t)row * (D_ * 2) + dq * 128 + gi * 4]);
    int gs = gi ^ (row & 31);
    *reinterpret_cast<float4*>((char*)ps_s + row * 512 + (gs << 4)) = v;
  }
  __syncthreads();

  const int tr = tid & 63;   // rule = lane
  const int tb = tid >> 6;   // wave -> 4 batch rows
  const int s31 = tr & 31;
  const char* pb = (const char*)ps_s + tr * 512;
  float facc[4] = {0.f, 0.f, 0.f, 0.f};

#pragma unroll
  for (int d4 = 0; d4 < 16; ++d4) {
    float4 psa = *reinterpret_cast<const float4*>(pb + ((((d4 * 2) ^ s31)) << 4));
    float4 psb = *reinterpret_cast<const float4*>(pb + ((((d4 * 2 + 1) ^ s31)) << 4));
#pragma unroll
    for (int i = 0; i < 4; ++i) {
      float4 xv = *reinterpret_cast<const float4*>(&x_s[(tb * 4 + i) * 68 + d4 * 4]);
      float u0 = fmaf(xv.x, psa.x, psa.y);
      float u1 = fmaf(xv.y, psa.z, psa.w);
      float u2 = fmaf(xv.z, psb.x, psb.y);
      float u3 = fmaf(xv.w, psb.z, psb.w);
      facc[i] += exp2f(-(u0 * u0)) + exp2f(-(u1 * u1)) +
                 exp2f(-(u2 * u2)) + exp2f(-(u3 * u3));
    }
  }
#pragma unroll
  for (int i = 0; i < 4; ++i)
    atomicAdd(&fire[(size_t)(b0 + tb * 4 + i) * R_ + tr], facc[i]);
}

// ---------------- softmax over rules, in place on fire buffer ----------------
__global__ void softmax_kernel(float* __restrict__ fire) {
  const int b = blockIdx.x * 4 + (threadIdx.x >> 6);
  const int r = threadIdx.x & 63;
  float v = fire[(size_t)b * R_ + r];
  float m = v;
#pragma unroll
  for (int off = 32; off; off >>= 1) m = fmaxf(m, __shfl_xor(m, off, 64));
  float e = exp2f((v - m) * 1.4426950408889634f);
  float s = e;
#pragma unroll
  for (int off = 32; off; off >>= 1) s += __shfl_xor(s, off, 64);
  fire[(size_t)b * R_ + r] = e / s;
}

// ---------------- fused rule-GEMM + relu + fire-weighted combine ----------------
__global__ __launch_bounds__(512, 2) void gemm_kernel(
    const unsigned short* __restrict__ xw, const unsigned short* __restrict__ wt,
    const float* __restrict__ fire, const float* __restrict__ bias,
    float* __restrict__ out) {
  __shared__ __align__(16) unsigned short x_s[2][128 * 64];
  __shared__ __align__(16) unsigned short w_s[2][128 * 64];
  __shared__ float fire_s[128 * 8];
  __shared__ float bias_s[8 * 128];

  const int tid = threadIdx.x;
  const int bm = blockIdx.x;   // 0..31 batch-row block
  const int rg = blockIdx.y;   // 0..7  rule group (8 rules)
  const int b0 = bm * 128;

  {
    int t = tid;
#pragma unroll
    for (int q = 0; q < 2; ++q, t += 512) {
      int row = t >> 3, g = t & 7;
      fire_s[t] = fire[(size_t)(b0 + row) * R_ + rg * 8 + g];
    }
    t = tid;
#pragma unroll
    for (int q = 0; q < 2; ++q, t += 512) {
      bias_s[t] = bias[rg * 8 * C_ + t];
    }
  }

  const int wid = tid >> 6, lane = tid & 63;
  const int wm = wid >> 2, wn = wid & 3;           // 2 x 4 wave grid, wave tile 64x32
  const int l16 = lane & 15, lhi = lane >> 4;

  // ds_read byte offsets (XOR-swizzled granules within 128B rows)
  int offA[4][2], offB[2][2];
#pragma unroll
  for (int m = 0; m < 4; ++m) {
    int row = wm * 64 + m * 16 + l16;
#pragma unroll
    for (int ks = 0; ks < 2; ++ks)
      offA[m][ks] = row * 128 + (((ks * 4 + lhi) ^ (row & 7)) << 4);
  }
#pragma unroll
  for (int n = 0; n < 2; ++n) {
    int row = wn * 32 + n * 16 + l16;
#pragma unroll
    for (int ks = 0; ks < 2; ++ks)
      offB[n][ks] = row * 128 + (((ks * 4 + lhi) ^ (row & 7)) << 4);
  }

  const unsigned short* xsrc = xw + (size_t)b0 * D_;

  float tot[4][2][4];
#pragma unroll
  for (int m = 0; m < 4; ++m)
#pragma unroll
    for (int n = 0; n < 2; ++n)
#pragma unroll
      for (int j = 0; j < 4; ++j) tot[m][n][j] = 0.f;

  f32x4 acc[4][2];

  // stage one 128x64 bf16 tile: linear LDS dest, inverse-swizzled global source
  auto stage = [&](unsigned short* lds, const unsigned short* src, int kc) {
#pragma unroll
    for (int t2 = 0; t2 < 2; ++t2) {
      int ch = t2 * 512 + tid;          // 1024 x 16B chunks
      int row = ch >> 3, g = ch & 7;
      const unsigned short* ga = src + (size_t)row * D_ + kc + ((g ^ (row & 7)) << 3);
      __builtin_amdgcn_global_load_lds(
          (const __attribute__((address_space(1))) void*)ga,
          (__attribute__((address_space(3))) void*)(lds + ch * 8), 16, 0, 0);
    }
  };

  stage(x_s[0], xsrc, 0);
  stage(w_s[0], wt + (size_t)(rg * 8) * C_ * D_, 0);
  asm volatile("s_waitcnt vmcnt(0)" ::: "memory");
  __syncthreads();

  int cur = 0;
  for (int s = 0; s < 64; ++s) {
    const int g = s >> 3, kk = s & 7;
    if (kk == 0) {
#pragma unroll
      for (int m = 0; m < 4; ++m)
#pragma unroll
        for (int n = 0; n < 2; ++n)
          acc[m][n] = f32x4{0.f, 0.f, 0.f, 0.f};
    }
    if (s + 1 < 64) {
      const int s1 = s + 1;
      stage(x_s[cur ^ 1], xsrc, (s1 & 7) * 64);
      stage(w_s[cur ^ 1], wt + (size_t)(rg * 8 + (s1 >> 3)) * C_ * D_, (s1 & 7) * 64);
    }
    const char* xb = (const char*)x_s[cur];
    const char* wb = (const char*)w_s[cur];
    bf16x8 av[4][2], bv[2][2];
#pragma unroll
    for (int m = 0; m < 4; ++m)
#pragma unroll
      for (int ks = 0; ks < 2; ++ks)
        av[m][ks] = *reinterpret_cast<const bf16x8*>(xb + offA[m][ks]);
#pragma unroll
    for (int n = 0; n < 2; ++n)
#pragma unroll
      for (int ks = 0; ks < 2; ++ks)
        bv[n][ks] = *reinterpret_cast<const bf16x8*>(wb + offB[n][ks]);
#pragma unroll
    for (int ks = 0; ks < 2; ++ks)
#pragma unroll
      for (int m = 0; m < 4; ++m)
#pragma unroll
        for (int n = 0; n < 2; ++n)
          acc[m][n] = __builtin_amdgcn_mfma_f32_16x16x32_bf16(av[m][ks], bv[n][ks], acc[m][n], 0, 0, 0);
    if (kk == 7) {  // rule g finished: relu(+bias) * fire, accumulate
#pragma unroll
      for (int m = 0; m < 4; ++m)
#pragma unroll
        for (int n = 0; n < 2; ++n) {
          int col = wn * 32 + n * 16 + l16;
          float bi = bias_s[g * 128 + col];
#pragma unroll
          for (int j = 0; j < 4; ++j) {
            int rowl = wm * 64 + m * 16 + lhi * 4 + j;
            float v = acc[m][n][j] + bi;
            v = fmaxf(v, 0.f);
            tot[m][n][j] += v * fire_s[rowl * 8 + g];
          }
        }
    }
    asm volatile("s_waitcnt vmcnt(0)" ::: "memory");
    __syncthreads();
    cur ^= 1;
  }

#pragma unroll
  for (int m = 0; m < 4; ++m)
#pragma unroll
    for (int n = 0; n < 2; ++n) {
      int col = wn * 32 + n * 16 + l16;
#pragma unroll
      for (int j = 0; j < 4; ++j) {
        int rowl = wm * 64 + m * 16 + lhi * 4 + j;
        atomicAdd(&out[(size_t)(b0 + rowl) * C_ + col], tot[m][n][j]);
      }
    }
}

extern "C" void kernel_launch(void* const* d_in, const int* in_sizes, int n_in,
                              void* d_out, int out_size, void* d_ws, size_t ws_size,
                              hipStream_t stream) {
  const float* x     = (const float*)d_in[0];
  const float* proto = (const float*)d_in[1];
  const float* var   = (const float*)d_in[2];
  const float* W     = (const float*)d_in[3];
  const float* bias  = (const float*)d_in[4];
  float* out  = (float*)d_out;
  float* fire = out + (size_t)B_ * C_;   // second output region (also fs_ini accumulator)

  const size_t WS_X  = (size_t)B_ * D_ * sizeof(unsigned short);       // 4 MiB
  const size_t WS_WT = (size_t)R_ * C_ * D_ * sizeof(unsigned short);  // 8 MiB
  const size_t WS_PS = (size_t)R_ * D_ * 2 * sizeof(float);            // 256 KiB
  if (ws_size < WS_X + WS_WT + WS_PS) return;  // insufficient scratch -> visible failure

  unsigned short* xw  = (unsigned short*)d_ws;
  unsigned short* wtp = (unsigned short*)((char*)d_ws + WS_X);
  float*          ps  = (float*)((char*)d_ws + WS_X + WS_WT);

  // zero BOTH output regions: out accumulates gemm atomics, fire accumulates fs partials
  hipMemsetAsync(d_out, 0, (size_t)out_size * sizeof(float), stream);
  prep_x_kernel<<<dim3((B_ * D_ / 4) / 256), dim3(256), 0, stream>>>(x, xw);
  prep_w_kernel<<<dim3(R_ * 64), dim3(256), 0, stream>>>(W, wtp);
  prep_ps_kernel<<<dim3(R_ * D_ / 256), dim3(256), 0, stream>>>(proto, var, ps);
  fs_partial_kernel<<<dim3(B_ / 16, 8), dim3(256), 0, stream>>>(x, ps, fire);
  softmax_kernel<<<dim3(B_ / 4), dim3(256), 0, stream>>>(fire);
  gemm_kernel<<<dim3(B_ / 128, R_ / 8), dim3(512), 0, stream>>>(xw, wtp, fire, bias, out);
}

// Round 3
// 121.259 us; speedup vs baseline: 1.3146x; 1.0975x over previous
//
#include <hip/hip_runtime.h>
#include <hip/hip_bf16.h>
#include <cmath>

#define R_ 64
#define B_ 4096
#define D_ 512
#define C_ 128

typedef __attribute__((ext_vector_type(8))) short bf16x8;
typedef __attribute__((ext_vector_type(4))) float f32x4;

__device__ __forceinline__ unsigned short f2bf(float f) {
  union { float f; unsigned u; } x; x.f = f;
  unsigned r = (x.u + 0x7FFFu + ((x.u >> 16) & 1u)) >> 16;
  return (unsigned short)r;
}

// ---------------- prep: x f32 -> bf16 ----------------
__global__ void prep_x_kernel(const float* __restrict__ x, unsigned short* __restrict__ xw) {
  int i = blockIdx.x * 256 + threadIdx.x;          // float4 index, exact count
  float4 v = reinterpret_cast<const float4*>(x)[i];
  ushort4 o;
  o.x = f2bf(v.x); o.y = f2bf(v.y); o.z = f2bf(v.z); o.w = f2bf(v.w);
  reinterpret_cast<ushort4*>(xw)[i] = o;
}

// ---------------- prep: W[r][d][c] f32 -> W^T[r][c][d] bf16 ----------------
__global__ void prep_w_kernel(const float* __restrict__ W, unsigned short* __restrict__ wt) {
  __shared__ float t[32][33];
  int bx = blockIdx.x;
  int r = bx >> 6;
  int rem = bx & 63;
  int d0 = (rem >> 2) << 5;   // 16 d-tiles of 32
  int c0 = (rem & 3) << 5;    // 4 c-tiles of 32
  int tx = threadIdx.x & 31, ty = threadIdx.x >> 5;  // 32 x 8
  const float* Wr = W + (size_t)r * D_ * C_;
#pragma unroll
  for (int q = 0; q < 4; ++q) {
    int dl = q * 8 + ty;
    t[dl][tx] = Wr[(size_t)(d0 + dl) * C_ + c0 + tx];
  }
  __syncthreads();
  unsigned short* wtr = wt + (size_t)r * C_ * D_;
#pragma unroll
  for (int q = 0; q < 4; ++q) {
    int cl = q * 8 + ty;
    float v = t[tx][cl];                         // transposed read, pad-33 conflict-free
    wtr[(size_t)(c0 + cl) * D_ + d0 + tx] = f2bf(v);
  }
}

// ---------------- prep: (s, -p*s) per (rule, dim) ----------------
// s = sqrt(log2 e)/clip(v)  so  exp2(-(fma(x,s,nsp))^2) = exp(-(x-p)^2/v^2) = m^2
__global__ void prep_ps_kernel(const float* __restrict__ proto, const float* __restrict__ var,
                               float* __restrict__ ps) {
  int i = blockIdx.x * 256 + threadIdx.x;          // R*D elements
  float v = fminf(fmaxf(var[i], 1e-4f), 0.1f);
  float s = 1.2011224087864498f / v;
  float2 o; o.x = s; o.y = -proto[i] * s;
  reinterpret_cast<float2*>(ps)[i] = o;
}

// ---------------- antecedent partial: fs_ini accumulation ----------------
// grid (B/16, 8): 16 batch rows x 64 rules x 64 dims per block; atomics into fire buf.
__global__ __launch_bounds__(256, 4) void fs_partial_kernel(
    const float* __restrict__ x, const float* __restrict__ ps,
    float* __restrict__ fire) {
  __shared__ float x_s[16 * 68];
  __shared__ __align__(16) float ps_s[64 * 128];   // [rule][dim*2], XOR-swizzled granules
  const int tid = threadIdx.x;
  const int b0 = blockIdx.x * 16;
  const int dq = blockIdx.y;                       // dims dq*64 .. dq*64+63

  {  // stage x tile: 16 rows x 64 dims
    int row = tid >> 4, c4 = tid & 15;
    float4 v = *reinterpret_cast<const float4*>(&x[(size_t)(b0 + row) * D_ + dq * 64 + c4 * 4]);
    *reinterpret_cast<float4*>(&x_s[row * 68 + c4 * 4]) = v;
  }
#pragma unroll
  for (int k = 0; k < 8; ++k) {  // stage ps tile: 64 rules x 32 granules(16B), swizzled
    int g = tid + k * 256;
    int row = g >> 5, gi = g & 31;
    float4 v = *reinterpret_cast<const float4*>(&ps[(size_t)row * (D_ * 2) + dq * 128 + gi * 4]);
    int gs = gi ^ (row & 31);
    *reinterpret_cast<float4*>((char*)ps_s + row * 512 + (gs << 4)) = v;
  }
  __syncthreads();

  const int tr = tid & 63;   // rule = lane
  const int tb = tid >> 6;   // wave -> 4 batch rows
  const int s31 = tr & 31;
  const char* pb = (const char*)ps_s + tr * 512;
  float facc[4] = {0.f, 0.f, 0.f, 0.f};

#pragma unroll
  for (int d4 = 0; d4 < 16; ++d4) {
    float4 psa = *reinterpret_cast<const float4*>(pb + ((((d4 * 2) ^ s31)) << 4));
    float4 psb = *reinterpret_cast<const float4*>(pb + ((((d4 * 2 + 1) ^ s31)) << 4));
#pragma unroll
    for (int i = 0; i < 4; ++i) {
      float4 xv = *reinterpret_cast<const float4*>(&x_s[(tb * 4 + i) * 68 + d4 * 4]);
      float u0 = fmaf(xv.x, psa.x, psa.y);
      float u1 = fmaf(xv.y, psa.z, psa.w);
      float u2 = fmaf(xv.z, psb.x, psb.y);
      float u3 = fmaf(xv.w, psb.z, psb.w);
      facc[i] += exp2f(-(u0 * u0)) + exp2f(-(u1 * u1)) +
                 exp2f(-(u2 * u2)) + exp2f(-(u3 * u3));
    }
  }
#pragma unroll
  for (int i = 0; i < 4; ++i)
    atomicAdd(&fire[(size_t)(b0 + tb * 4 + i) * R_ + tr], facc[i]);
}

// ---------------- softmax over rules, in place on fire buffer ----------------
__global__ void softmax_kernel(float* __restrict__ fire) {
  const int b = blockIdx.x * 4 + (threadIdx.x >> 6);
  const int r = threadIdx.x & 63;
  float v = fire[(size_t)b * R_ + r];
  float m = v;
#pragma unroll
  for (int off = 32; off; off >>= 1) m = fmaxf(m, __shfl_xor(m, off, 64));
  float e = exp2f((v - m) * 1.4426950408889634f);
  float s = e;
#pragma unroll
  for (int off = 32; off; off >>= 1) s += __shfl_xor(s, off, 64);
  fire[(size_t)b * R_ + r] = e / s;
}

// ---------------- fused rule-GEMM + relu + fire-weighted combine ----------------
// BM=128, BN=C=128, BK=64. 4 waves (2x2), wave tile 64x64. 4 rules per block.
// grid (32 bm, 16 rg) = 512 blocks -> 2 blocks/CU (LDS 68KB).
__global__ __launch_bounds__(256, 2) void gemm_kernel(
    const unsigned short* __restrict__ xw, const unsigned short* __restrict__ wt,
    const float* __restrict__ fire, const float* __restrict__ bias,
    float* __restrict__ out) {
  __shared__ __align__(16) unsigned short x_s[2][128 * 64];
  __shared__ __align__(16) unsigned short w_s[2][128 * 64];
  __shared__ float fire_s[128 * 4];
  __shared__ float bias_s[4 * 128];

  const int tid = threadIdx.x;
  const int bm = blockIdx.x;   // 0..31 batch-row block
  const int rg = blockIdx.y;   // 0..15 rule group (4 rules)
  const int b0 = bm * 128;

  {
    for (int t = tid; t < 512; t += 256) {
      int row = t >> 2, g = t & 3;
      fire_s[t] = fire[(size_t)(b0 + row) * R_ + rg * 4 + g];
    }
    for (int t = tid; t < 512; t += 256) {
      bias_s[t] = bias[rg * 4 * C_ + t];
    }
  }

  const int wid = tid >> 6, lane = tid & 63;
  const int wm = wid >> 1, wn = wid & 1;           // 2 x 2 wave grid, wave tile 64x64
  const int l16 = lane & 15, lhi = lane >> 4;

  // ds_read byte offsets (XOR-swizzled granules within 128B rows)
  int offA[4][2], offB[4][2];
#pragma unroll
  for (int m = 0; m < 4; ++m) {
    int row = wm * 64 + m * 16 + l16;
#pragma unroll
    for (int ks = 0; ks < 2; ++ks)
      offA[m][ks] = row * 128 + (((ks * 4 + lhi) ^ (row & 7)) << 4);
  }
#pragma unroll
  for (int n = 0; n < 4; ++n) {
    int row = wn * 64 + n * 16 + l16;
#pragma unroll
    for (int ks = 0; ks < 2; ++ks)
      offB[n][ks] = row * 128 + (((ks * 4 + lhi) ^ (row & 7)) << 4);
  }

  const unsigned short* xsrc = xw + (size_t)b0 * D_;
  const unsigned short* wbase = wt + (size_t)(rg * 4) * C_ * D_;

  float tot[4][4][4];
#pragma unroll
  for (int m = 0; m < 4; ++m)
#pragma unroll
    for (int n = 0; n < 4; ++n)
#pragma unroll
      for (int j = 0; j < 4; ++j) tot[m][n][j] = 0.f;

  f32x4 acc[4][4];

  // stage one 128x64 bf16 tile: linear LDS dest, inverse-swizzled global source
  auto stage = [&](unsigned short* lds, const unsigned short* src, int kc) {
#pragma unroll
    for (int q = 0; q < 4; ++q) {
      int ch = q * 256 + tid;          // 1024 x 16B chunks
      int row = ch >> 3, g = ch & 7;
      const unsigned short* ga = src + (size_t)row * D_ + kc + ((g ^ (row & 7)) << 3);
      __builtin_amdgcn_global_load_lds(
          (const __attribute__((address_space(1))) void*)ga,
          (__attribute__((address_space(3))) void*)(lds + ch * 8), 16, 0, 0);
    }
  };

  stage(x_s[0], xsrc, 0);
  stage(w_s[0], wbase, 0);
  asm volatile("s_waitcnt vmcnt(0)" ::: "memory");
  __syncthreads();

  int cur = 0;
  for (int s = 0; s < 32; ++s) {
    const int g = s >> 3, kk = s & 7;
    if (kk == 0) {
#pragma unroll
      for (int m = 0; m < 4; ++m)
#pragma unroll
        for (int n = 0; n < 4; ++n)
          acc[m][n] = f32x4{0.f, 0.f, 0.f, 0.f};
    }
    if (s + 1 < 32) {
      const int s1 = s + 1;
      stage(x_s[cur ^ 1], xsrc, (s1 & 7) * 64);
      stage(w_s[cur ^ 1], wbase + (size_t)(s1 >> 3) * C_ * D_, (s1 & 7) * 64);
    }
    const char* xb = (const char*)x_s[cur];
    const char* wb = (const char*)w_s[cur];
    bf16x8 av[4][2], bv[4][2];
#pragma unroll
    for (int m = 0; m < 4; ++m)
#pragma unroll
      for (int ks = 0; ks < 2; ++ks)
        av[m][ks] = *reinterpret_cast<const bf16x8*>(xb + offA[m][ks]);
#pragma unroll
    for (int n = 0; n < 4; ++n)
#pragma unroll
      for (int ks = 0; ks < 2; ++ks)
        bv[n][ks] = *reinterpret_cast<const bf16x8*>(wb + offB[n][ks]);
#pragma unroll
    for (int ks = 0; ks < 2; ++ks)
#pragma unroll
      for (int m = 0; m < 4; ++m)
#pragma unroll
        for (int n = 0; n < 4; ++n)
          acc[m][n] = __builtin_amdgcn_mfma_f32_16x16x32_bf16(av[m][ks], bv[n][ks], acc[m][n], 0, 0, 0);
    if (kk == 7) {  // rule g finished: relu(+bias) * fire, accumulate (hides under drain)
#pragma unroll
      for (int m = 0; m < 4; ++m)
#pragma unroll
        for (int n = 0; n < 4; ++n) {
          int col = wn * 64 + n * 16 + l16;
          float bi = bias_s[g * 128 + col];
#pragma unroll
          for (int j = 0; j < 4; ++j) {
            int rowl = wm * 64 + m * 16 + lhi * 4 + j;
            float v = acc[m][n][j] + bi;
            v = fmaxf(v, 0.f);
            tot[m][n][j] += v * fire_s[rowl * 4 + g];
          }
        }
    }
    asm volatile("s_waitcnt vmcnt(0)" ::: "memory");
    __syncthreads();
    cur ^= 1;
  }

#pragma unroll
  for (int m = 0; m < 4; ++m)
#pragma unroll
    for (int n = 0; n < 4; ++n) {
      int col = wn * 64 + n * 16 + l16;
#pragma unroll
      for (int j = 0; j < 4; ++j) {
        int rowl = wm * 64 + m * 16 + lhi * 4 + j;
        atomicAdd(&out[(size_t)(b0 + rowl) * C_ + col], tot[m][n][j]);
      }
    }
}

extern "C" void kernel_launch(void* const* d_in, const int* in_sizes, int n_in,
                              void* d_out, int out_size, void* d_ws, size_t ws_size,
                              hipStream_t stream) {
  const float* x     = (const float*)d_in[0];
  const float* proto = (const float*)d_in[1];
  const float* var   = (const float*)d_in[2];
  const float* W     = (const float*)d_in[3];
  const float* bias  = (const float*)d_in[4];
  float* out  = (float*)d_out;
  float* fire = out + (size_t)B_ * C_;   // second output region (also fs_ini accumulator)

  const size_t WS_X  = (size_t)B_ * D_ * sizeof(unsigned short);       // 4 MiB
  const size_t WS_WT = (size_t)R_ * C_ * D_ * sizeof(unsigned short);  // 8 MiB
  const size_t WS_PS = (size_t)R_ * D_ * 2 * sizeof(float);            // 256 KiB
  if (ws_size < WS_X + WS_WT + WS_PS) return;  // insufficient scratch -> visible failure

  unsigned short* xw  = (unsigned short*)d_ws;
  unsigned short* wtp = (unsigned short*)((char*)d_ws + WS_X);
  float*          ps  = (float*)((char*)d_ws + WS_X + WS_WT);

  // zero BOTH output regions: out accumulates gemm atomics, fire accumulates fs partials
  hipMemsetAsync(d_out, 0, (size_t)out_size * sizeof(float), stream);
  prep_x_kernel<<<dim3((B_ * D_ / 4) / 256), dim3(256), 0, stream>>>(x, xw);
  prep_w_kernel<<<dim3(R_ * 64), dim3(256), 0, stream>>>(W, wtp);
  prep_ps_kernel<<<dim3(R_ * D_ / 256), dim3(256), 0, stream>>>(proto, var, ps);
  fs_partial_kernel<<<dim3(B_ / 16, 8), dim3(256), 0, stream>>>(x, ps, fire);
  softmax_kernel<<<dim3(B_ / 4), dim3(256), 0, stream>>>(fire);
  gemm_kernel<<<dim3(B_ / 128, R_ / 4), dim3(256), 0, stream>>>(xw, wtp, fire, bias, out);
}